// Round 1
// baseline (230.132 us; speedup 1.0000x reference)
//
#include <hip/hip_runtime.h>
#include <hip/hip_bf16.h>

#define THREADS 256
#define DIM 16

// ---------------------------------------------------------------------------
// Precompute squared norms of the `cols` points (particles): ||p_j||^2
// ---------------------------------------------------------------------------
__global__ __launch_bounds__(THREADS) void norms_kernel(
    const float* __restrict__ pts, float* __restrict__ outn, int n)
{
    int i = blockIdx.x * THREADS + threadIdx.x;
    if (i >= n) return;
    const float4* p = reinterpret_cast<const float4*>(pts) + (size_t)i * 4;
    float s = 0.f;
#pragma unroll
    for (int q = 0; q < 4; ++q) {
        float4 t = p[q];
        s = fmaf(t.x, t.x, s);
        s = fmaf(t.y, t.y, s);
        s = fmaf(t.z, t.z, s);
        s = fmaf(t.w, t.w, s);
    }
    outn[i] = s;
}

// ---------------------------------------------------------------------------
// Sum over a [rows x cols-chunk] tile of exp(-0.5 * max(||r_i - c_j||^2, 0)).
// Each thread owns one row (16 floats in VGPRs); the j loop is wave-uniform so
// cols[j] / cnorm[j] compile to scalar (s_load) reads from the L2-resident
// particle array. Per-block partial sum written as double to `partials`.
// ---------------------------------------------------------------------------
__global__ __launch_bounds__(THREADS) void gram_sum_kernel(
    const float* __restrict__ rows, int nrows,
    const float* __restrict__ cols, int ncols,
    const float* __restrict__ cnorm,
    int chunk,
    double* __restrict__ partials)
{
    const int row = blockIdx.x * THREADS + threadIdx.x;

    float xv[DIM];
    float x2 = 0.f;
    if (row < nrows) {
        const float4* xp = reinterpret_cast<const float4*>(rows) + (size_t)row * 4;
#pragma unroll
        for (int q = 0; q < 4; ++q) {
            float4 t = xp[q];
            xv[4 * q + 0] = t.x;
            xv[4 * q + 1] = t.y;
            xv[4 * q + 2] = t.z;
            xv[4 * q + 3] = t.w;
        }
#pragma unroll
        for (int k = 0; k < DIM; ++k) x2 = fmaf(xv[k], xv[k], x2);
    }

    float acc = 0.f;
    if (row < nrows) {
        const int j0 = blockIdx.y * chunk;
        const int j1 = min(j0 + chunk, ncols);
        for (int j = j0; j < j1; ++j) {
            const float* p = cols + (size_t)j * DIM;
            // 4-way split dot for ILP (breaks the 16-deep fma dependency chain)
            float d0 = xv[0] * p[0];
            float d1 = xv[1] * p[1];
            float d2 = xv[2] * p[2];
            float d3 = xv[3] * p[3];
#pragma unroll
            for (int k = 4; k < DIM; k += 4) {
                d0 = fmaf(xv[k + 0], p[k + 0], d0);
                d1 = fmaf(xv[k + 1], p[k + 1], d1);
                d2 = fmaf(xv[k + 2], p[k + 2], d2);
                d3 = fmaf(xv[k + 3], p[k + 3], d3);
            }
            float dot = (d0 + d1) + (d2 + d3);
            float sq = fmaxf(fmaf(-2.f, dot, x2 + cnorm[j]), 0.f);
            acc += __expf(-0.5f * sq);
        }
    }

    // Block reduction, f32 partial -> f64 (precision-critical: t1 and t2
    // nearly cancel; cross-thread accumulation must be double).
    double v = (double)acc;
#pragma unroll
    for (int off = 32; off > 0; off >>= 1) v += __shfl_down(v, off);

    __shared__ double sred[THREADS / 64];
    const int lane = threadIdx.x & 63;
    const int wid = threadIdx.x >> 6;
    if (lane == 0) sred[wid] = v;
    __syncthreads();
    if (threadIdx.x == 0) {
        double tot = 0.0;
#pragma unroll
        for (int w = 0; w < THREADS / 64; ++w) tot += sred[w];
        partials[(size_t)blockIdx.y * gridDim.x + blockIdx.x] = tot;
    }
}

// ---------------------------------------------------------------------------
// Final reduction of the block partials:
//   out = sc1 * sum(partials[0:n1]) - sc2 * sum(partials[n1:n1+n2])
// ---------------------------------------------------------------------------
__global__ __launch_bounds__(THREADS) void finalize_kernel(
    const double* __restrict__ partials, int n1, int n2,
    double sc1, double sc2, float* __restrict__ out)
{
    double s1 = 0.0, s2 = 0.0;
    for (int i = threadIdx.x; i < n1; i += THREADS) s1 += partials[i];
    for (int i = threadIdx.x; i < n2; i += THREADS) s2 += partials[n1 + i];
    double v = s1 * sc1 - s2 * sc2;  // linear: summing per-thread v == combine of sums
#pragma unroll
    for (int off = 32; off > 0; off >>= 1) v += __shfl_down(v, off);

    __shared__ double sred[THREADS / 64];
    const int lane = threadIdx.x & 63;
    const int wid = threadIdx.x >> 6;
    if (lane == 0) sred[wid] = v;
    __syncthreads();
    if (threadIdx.x == 0) {
        double tot = 0.0;
#pragma unroll
        for (int w = 0; w < THREADS / 64; ++w) tot += sred[w];
        out[0] = (float)tot;
    }
}

extern "C" void kernel_launch(void* const* d_in, const int* in_sizes, int n_in,
                              void* d_out, int out_size, void* d_ws, size_t ws_size,
                              hipStream_t stream) {
    const float* x = (const float*)d_in[0];         // [NX, 16]
    const float* particles = (const float*)d_in[1]; // [NP, 16]
    float* out = (float*)d_out;

    const int NX = in_sizes[0] / DIM;  // 32768
    const int NP = in_sizes[1] / DIM;  // 8192

    const int nb_x = (NX + THREADS - 1) / THREADS;  // 128
    const int nb_p = (NP + THREADS - 1) / THREADS;  // 32
    const int jchunks = nb_p;                       // 32 chunks of 256 cols
    const int chunk = (NP + jchunks - 1) / jchunks; // 256

    const int n1 = nb_p * jchunks;  // 1024 partials for t1 (P x P)
    const int n2 = nb_x * jchunks;  // 4096 partials for t2 (X x P)

    double* partials = (double*)d_ws;
    float* pnorms = (float*)((char*)d_ws + (size_t)(n1 + n2) * sizeof(double));

    // 1) particle squared norms
    norms_kernel<<<nb_p, THREADS, 0, stream>>>(particles, pnorms, NP);

    // 2) t1: particles x particles
    gram_sum_kernel<<<dim3(nb_p, jchunks), THREADS, 0, stream>>>(
        particles, NP, particles, NP, pnorms, chunk, partials);

    // 3) t2: x x particles
    gram_sum_kernel<<<dim3(nb_x, jchunks), THREADS, 0, stream>>>(
        x, NX, particles, NP, pnorms, chunk, partials + n1);

    // 4) combine: out = s1/(NP*NP) - 2*s2/(NX*NP)
    finalize_kernel<<<1, THREADS, 0, stream>>>(
        partials, n1, n2,
        1.0 / ((double)NP * (double)NP),
        2.0 / ((double)NX * (double)NP),
        out);
}

// Round 2
// 111.201 us; speedup vs baseline: 2.0695x; 2.0695x over previous
//
#include <hip/hip_runtime.h>
#include <hip/hip_bf16.h>

#define THREADS 256
#define DIM 16

typedef __attribute__((ext_vector_type(8))) short bf16x8;
typedef __attribute__((ext_vector_type(16))) float f32x16;

// ---------------------------------------------------------------------------
// Prep: convert f32 points -> bf16 (round-to-nearest-even; truncation would
// bias every coordinate by -2^-9 and push ~4.6e-6 into t1-t2), and compute
// squared norms FROM THE ROUNDED VALUES (keeps the t1 diagonal exact: MFMA
// dot(p~,p~) vs 2*||p~||^2 cancels to ~ulp).
// ---------------------------------------------------------------------------
__global__ __launch_bounds__(THREADS) void prep_kernel(
    const float* __restrict__ x, int nx,
    const float* __restrict__ p, int np,
    short* __restrict__ xb, float* __restrict__ xn,
    short* __restrict__ pb, float* __restrict__ pn)
{
    int i = blockIdx.x * THREADS + threadIdx.x;
    const float* src;
    short* db;
    float* dn;
    if (i < nx) {
        src = x + (size_t)i * DIM;
        db = xb + (size_t)i * DIM;
        dn = xn + i;
    } else if (i < nx + np) {
        int j = i - nx;
        src = p + (size_t)j * DIM;
        db = pb + (size_t)j * DIM;
        dn = pn + j;
    } else {
        return;
    }

    float nrm = 0.f;
    bf16x8 lo, hi;
#pragma unroll
    for (int k = 0; k < DIM; ++k) {
        float f = src[k];
        unsigned u = __float_as_uint(f);
        unsigned short r = (unsigned short)((u + 0x7FFFu + ((u >> 16) & 1u)) >> 16); // RNE
        float fr = __uint_as_float((unsigned)r << 16);
        nrm = fmaf(fr, fr, nrm);
        if (k < 8) lo[k] = (short)r; else hi[k - 8] = (short)r;
    }
    *(bf16x8*)db = lo;
    *((bf16x8*)db + 1) = hi;
    *dn = nrm;
}

// ---------------------------------------------------------------------------
// Gram sum via MFMA. v_mfma_f32_32x32x16_bf16: K=16 == DIM (no padding).
// Each wave owns one 32-row tile (A frag in 4 VGPRs, loaded once) and walks
// a chunk of 32-col tiles. Per tile: 1 MFMA (1024 dots) + per-element
// {fma, add, min, exp2, acc} on the VALU.
//   A frag: lane l holds rows[row0 + (l&31)], k = (l>>5)*8 + i
//   B frag: lane l holds cols[ct*32 + (l&31)], k = (l>>5)*8 + i
//   D:      lane l, reg r -> row = (r&3) + 8*(r>>2) + 4*(l>>5), col = l&31
// exp(-g*max(sq,0)) with sq = xn + pn - 2d  ==>  exp2(min(L2E*d - HL2E*(xn+pn), 0))
// ---------------------------------------------------------------------------
__global__ __launch_bounds__(THREADS) void gram_mfma_kernel(
    const short* __restrict__ rowsb, const float* __restrict__ rown,
    const short* __restrict__ colsb, const float* __restrict__ coln,
    int ct_per_chunk,
    double* __restrict__ partials)
{
    const int lane = threadIdx.x & 63;
    const int wv   = threadIdx.x >> 6;
    const int l31  = lane & 31;
    const int half = lane >> 5;

    const int rt   = blockIdx.x * 4 + wv;   // 32-row tile index
    const int row0 = rt * 32;

    // A fragment (persistent)
    bf16x8 afrag = *(const bf16x8*)(rowsb + (size_t)(row0 + l31) * DIM + half * 8);

    // -HL2E * rownorm for each of this lane's 16 D rows
    const float L2E  = 1.44269504088896340736f;   // log2(e)      (x 2*gamma = 1)
    const float HL2E = 0.72134752044448170368f;   // 0.5*log2(e)  (gamma*log2e)
    float xnf[16];
#pragma unroll
    for (int r = 0; r < 16; ++r) {
        int rrow = (r & 3) + 8 * (r >> 2) + 4 * half;
        xnf[r] = -HL2E * rown[row0 + rrow];
    }

    float acc0 = 0.f, acc1 = 0.f, acc2 = 0.f, acc3 = 0.f;
    const f32x16 zero = {};

    const int ct0 = blockIdx.y * ct_per_chunk;
    for (int ct = ct0; ct < ct0 + ct_per_chunk; ++ct) {
        bf16x8 bfrag = *(const bf16x8*)(colsb + (size_t)(ct * 32 + l31) * DIM + half * 8);
        float pnf = -HL2E * coln[ct * 32 + l31];

        f32x16 d = __builtin_amdgcn_mfma_f32_32x32x16_bf16(afrag, bfrag, zero, 0, 0, 0);

#pragma unroll
        for (int r = 0; r < 16; ++r) {
            float arg = fminf(fmaf(L2E, d[r], xnf[r] + pnf), 0.f);
            float e = exp2f(arg);
            if ((r & 3) == 0) acc0 += e;
            else if ((r & 3) == 1) acc1 += e;
            else if ((r & 3) == 2) acc2 += e;
            else acc3 += e;
        }
    }

    // f64 cross-thread reduction (t1 and t2 nearly cancel in the output)
    double v = (double)((acc0 + acc1) + (acc2 + acc3));
#pragma unroll
    for (int off = 32; off > 0; off >>= 1) v += __shfl_down(v, off);

    __shared__ double sred[THREADS / 64];
    if (lane == 0) sred[wv] = v;
    __syncthreads();
    if (threadIdx.x == 0) {
        double tot = 0.0;
#pragma unroll
        for (int w = 0; w < THREADS / 64; ++w) tot += sred[w];
        partials[(size_t)blockIdx.y * gridDim.x + blockIdx.x] = tot;
    }
}

// ---------------------------------------------------------------------------
// out = sc1 * sum(partials[0:n1]) - sc2 * sum(partials[n1:n1+n2])
// ---------------------------------------------------------------------------
__global__ __launch_bounds__(THREADS) void finalize_kernel(
    const double* __restrict__ partials, int n1, int n2,
    double sc1, double sc2, float* __restrict__ out)
{
    double s1 = 0.0, s2 = 0.0;
    for (int i = threadIdx.x; i < n1; i += THREADS) s1 += partials[i];
    for (int i = threadIdx.x; i < n2; i += THREADS) s2 += partials[n1 + i];
    double v = s1 * sc1 - s2 * sc2;
#pragma unroll
    for (int off = 32; off > 0; off >>= 1) v += __shfl_down(v, off);

    __shared__ double sred[THREADS / 64];
    const int lane = threadIdx.x & 63;
    const int wid = threadIdx.x >> 6;
    if (lane == 0) sred[wid] = v;
    __syncthreads();
    if (threadIdx.x == 0) {
        double tot = 0.0;
#pragma unroll
        for (int w = 0; w < THREADS / 64; ++w) tot += sred[w];
        out[0] = (float)tot;
    }
}

extern "C" void kernel_launch(void* const* d_in, const int* in_sizes, int n_in,
                              void* d_out, int out_size, void* d_ws, size_t ws_size,
                              hipStream_t stream) {
    const float* x = (const float*)d_in[0];         // [NX, 16]
    const float* particles = (const float*)d_in[1]; // [NP, 16]
    float* out = (float*)d_out;

    const int NX = in_sizes[0] / DIM;  // 32768
    const int NP = in_sizes[1] / DIM;  // 8192

    // ---- workspace layout (all 16B-aligned by construction) ----
    char* ws = (char*)d_ws;
    double* partials = (double*)ws;                         // 4096 doubles = 32 KB
    float*  xn = (float*)(ws + 32768);                      // 128 KB
    float*  pn = (float*)(ws + 32768 + 131072);             // 32 KB
    short*  xb = (short*)(ws + 32768 + 131072 + 32768);     // 1 MB
    short*  pb = (short*)(ws + 32768 + 131072 + 32768 + 1048576); // 256 KB

    // ---- 1) convert + norms ----
    const int nprep = (NX + NP + THREADS - 1) / THREADS;    // 160 blocks
    prep_kernel<<<nprep, THREADS, 0, stream>>>(x, NX, particles, NP, xb, xn, pb, pn);

    // ---- 2) t1: P x P ----
    // row-tiles = NP/32 = 256 -> 64 blocks of 4 waves; 32 col-chunks of 8 tiles
    {
        dim3 grid(NP / 32 / 4, 32);
        int ct_per_chunk = (NP / 32) / 32;                  // 8
        gram_mfma_kernel<<<grid, THREADS, 0, stream>>>(
            pb, pn, pb, pn, ct_per_chunk, partials);
    }

    // ---- 3) t2: X x P ----
    // row-tiles = NX/32 = 1024 -> 256 blocks of 4 waves; 8 col-chunks of 32 tiles
    {
        dim3 grid(NX / 32 / 4, 8);
        int ct_per_chunk = (NP / 32) / 8;                   // 32
        gram_mfma_kernel<<<grid, THREADS, 0, stream>>>(
            xb, xn, pb, pn, ct_per_chunk, partials + 2048);
    }

    // ---- 4) combine ----
    finalize_kernel<<<1, THREADS, 0, stream>>>(
        partials, 2048, 2048,
        1.0 / ((double)NP * (double)NP),
        2.0 / ((double)NX * (double)NP),
        out);
}

// Round 3
// 62.856 us; speedup vs baseline: 3.6612x; 1.7691x over previous
//
#include <hip/hip_runtime.h>
#include <hip/hip_bf16.h>

#define THREADS 256
#define DIM 16

typedef __attribute__((ext_vector_type(8))) short bf16x8;
typedef __attribute__((ext_vector_type(16))) float f32x16;
typedef __attribute__((ext_vector_type(2))) float f32x2;

// ---------------------------------------------------------------------------
// Prep: f32 -> bf16 RNE (truncation would bias every coordinate by -2^-9 and
// inject ~4.6e-6 into t1-t2), norms computed FROM THE ROUNDED VALUES so the
// t1 diagonal cancels to ~ulp.
// ---------------------------------------------------------------------------
__global__ __launch_bounds__(THREADS) void prep_kernel(
    const float* __restrict__ x, int nx,
    const float* __restrict__ p, int np,
    short* __restrict__ xb, float* __restrict__ xn,
    short* __restrict__ pb, float* __restrict__ pn)
{
    int i = blockIdx.x * THREADS + threadIdx.x;
    const float* src;
    short* db;
    float* dn;
    if (i < nx) {
        src = x + (size_t)i * DIM;
        db = xb + (size_t)i * DIM;
        dn = xn + i;
    } else if (i < nx + np) {
        int j = i - nx;
        src = p + (size_t)j * DIM;
        db = pb + (size_t)j * DIM;
        dn = pn + j;
    } else {
        return;
    }

    float nrm = 0.f;
    bf16x8 lo, hi;
#pragma unroll
    for (int k = 0; k < DIM; ++k) {
        float f = src[k];
        unsigned u = __float_as_uint(f);
        unsigned short r = (unsigned short)((u + 0x7FFFu + ((u >> 16) & 1u)) >> 16); // RNE
        float fr = __uint_as_float((unsigned)r << 16);
        nrm = fmaf(fr, fr, nrm);
        if (k < 8) lo[k] = (short)r; else hi[k - 8] = (short)r;
    }
    *(bf16x8*)db = lo;
    *((bf16x8*)db + 1) = hi;
    *dn = nrm;
}

__device__ __forceinline__ float rawexp2(float a) { return __builtin_amdgcn_exp2f(a); }

// ---------------------------------------------------------------------------
// One 32-row-tile x ntiles 32-col-tiles gram partial sum.
// MFMA 32x32x16 bf16 (K == DIM, no padding).
//   A frag: lane l holds rows[row0 + (l&31)], k = (l>>5)*8 + i
//   B frag: lane l holds cols[ct*32 + (l&31)], k = (l>>5)*8 + i
//   D:      lane l, reg r -> row = (r&3) + 8*(r>>2) + 4*(l>>5), col = l&31
// Epilogue per element (floor form, raw v_exp_f32):
//   e   = exp2(L2E*d + xnf[r])           ; xnf = -0.5*log2e*rownorm
//   acc = fma(e, pf, acc)                ; pf  = exp2(-0.5*log2e*colnorm), 1/tile
// max(sq,0) clamp dropped: only the t1 diagonal can go negative (~1e-5),
// contributing ~2e-9 to the output. exp-split is bit-consistent on the
// diagonal because xnf and pf are identical expressions on identical norms.
// ---------------------------------------------------------------------------
__device__ __forceinline__ float gram_phase(
    const short* __restrict__ rowsb, const float* __restrict__ rown,
    const short* __restrict__ colsb, const float* __restrict__ coln,
    int row0, int ct0, int ntiles, int l31, int half)
{
    const float L2E  = 1.44269504088896340736f;
    const float HL2E = 0.72134752044448170368f;

    bf16x8 afrag = *(const bf16x8*)(rowsb + (size_t)(row0 + l31) * DIM + half * 8);

    float xnf[16];
#pragma unroll
    for (int r = 0; r < 16; ++r) {
        int rrow = (r & 3) + 8 * (r >> 2) + 4 * half;
        xnf[r] = -HL2E * rown[row0 + rrow];
    }

    const f32x16 zero = {};
    f32x2 acc2 = {0.f, 0.f};

    for (int ct = ct0; ct < ct0 + ntiles; ++ct) {
        bf16x8 bfrag = *(const bf16x8*)(colsb + (size_t)(ct * 32 + l31) * DIM + half * 8);
        float pf = rawexp2(-HL2E * coln[ct * 32 + l31]);

        f32x16 d = __builtin_amdgcn_mfma_f32_32x32x16_bf16(afrag, bfrag, zero, 0, 0, 0);

        float e[16];
#pragma unroll
        for (int r = 0; r < 16; ++r)
            e[r] = rawexp2(fmaf(L2E, d[r], xnf[r]));

        f32x2 pf2 = {pf, pf};
#pragma unroll
        for (int r = 0; r < 8; ++r) {
            f32x2 e2 = {e[2 * r], e[2 * r + 1]};
            acc2 = e2 * pf2 + acc2;   // v_pk_fma_f32 candidate
        }
    }
    return acc2.x + acc2.y;
}

// ---------------------------------------------------------------------------
// Fused t1 + t2: 8192 waves, each does exactly n1 t1-tiles and n2 t2-tiles
// (perfect balance). Per-thread f64 combine with scales, block partial out.
// ---------------------------------------------------------------------------
__global__ __launch_bounds__(THREADS) void gram_fused_kernel(
    const short* __restrict__ xb, const float* __restrict__ xn,
    const short* __restrict__ pb, const float* __restrict__ pn,
    int nrt_p, int n1,   // t1: row tiles of P (pow2), tiles per wave
    int nrt_x, int n2,   // t2: row tiles of X (pow2), tiles per wave
    double sc1, double sc2,
    double* __restrict__ partials)
{
    const int lane = threadIdx.x & 63;
    const int wv   = threadIdx.x >> 6;
    const int l31  = lane & 31;
    const int half = lane >> 5;
    const int w    = blockIdx.x * (THREADS / 64) + wv;

    // t1: P x P
    const int rt1 = w & (nrt_p - 1);
    const int c10 = (w / nrt_p) * n1;
    float acc1 = gram_phase(pb, pn, pb, pn, rt1 * 32, c10, n1, l31, half);

    // t2: X x P
    const int rt2 = w & (nrt_x - 1);
    const int c20 = (w / nrt_x) * n2;
    float acc2 = gram_phase(xb, xn, pb, pn, rt2 * 32, c20, n2, l31, half);

    double v = (double)acc1 * sc1 - (double)acc2 * sc2;
#pragma unroll
    for (int off = 32; off > 0; off >>= 1) v += __shfl_down(v, off);

    __shared__ double sred[THREADS / 64];
    if (lane == 0) sred[wv] = v;
    __syncthreads();
    if (threadIdx.x == 0) {
        double tot = 0.0;
#pragma unroll
        for (int q = 0; q < THREADS / 64; ++q) tot += sred[q];
        partials[blockIdx.x] = tot;
    }
}

// ---------------------------------------------------------------------------
// out = sum(partials[0:n])  (scales already applied per-wave)
// ---------------------------------------------------------------------------
__global__ __launch_bounds__(THREADS) void finalize_kernel(
    const double* __restrict__ partials, int n, float* __restrict__ out)
{
    double v = 0.0;
    for (int i = threadIdx.x; i < n; i += THREADS) v += partials[i];
#pragma unroll
    for (int off = 32; off > 0; off >>= 1) v += __shfl_down(v, off);

    __shared__ double sred[THREADS / 64];
    const int lane = threadIdx.x & 63;
    const int wid = threadIdx.x >> 6;
    if (lane == 0) sred[wid] = v;
    __syncthreads();
    if (threadIdx.x == 0) {
        double tot = 0.0;
#pragma unroll
        for (int q = 0; q < THREADS / 64; ++q) tot += sred[q];
        out[0] = (float)tot;
    }
}

extern "C" void kernel_launch(void* const* d_in, const int* in_sizes, int n_in,
                              void* d_out, int out_size, void* d_ws, size_t ws_size,
                              hipStream_t stream) {
    const float* x = (const float*)d_in[0];         // [NX, 16]
    const float* particles = (const float*)d_in[1]; // [NP, 16]
    float* out = (float*)d_out;

    const int NX = in_sizes[0] / DIM;  // 32768
    const int NP = in_sizes[1] / DIM;  // 8192

    const int nrt_x = NX / 32;         // 1024 row tiles (pow2)
    const int nrt_p = NP / 32;         // 256 row tiles (pow2)

    const int NBLOCKS = 2048;          // 8192 waves
    const int WAVES = NBLOCKS * (THREADS / 64);
    const int n1 = (nrt_p * nrt_p) / WAVES;  // 8 t1 tiles per wave
    const int n2 = (nrt_x * nrt_p) / WAVES;  // 32 t2 tiles per wave

    // ---- workspace layout (16B-aligned by construction) ----
    char* ws = (char*)d_ws;
    double* partials = (double*)ws;                           // 16 KB
    float*  xn = (float*)(ws + 32768);                        // 128 KB
    float*  pn = (float*)(ws + 32768 + 131072);               // 32 KB
    short*  xb = (short*)(ws + 32768 + 131072 + 32768);       // 1 MB
    short*  pb = (short*)(ws + 32768 + 131072 + 32768 + 1048576); // 256 KB

    // 1) convert + norms
    const int nprep = (NX + NP + THREADS - 1) / THREADS;
    prep_kernel<<<nprep, THREADS, 0, stream>>>(x, NX, particles, NP, xb, xn, pb, pn);

    // 2) fused gram sums (scales applied per-wave in f64)
    gram_fused_kernel<<<NBLOCKS, THREADS, 0, stream>>>(
        xb, xn, pb, pn,
        nrt_p, n1, nrt_x, n2,
        1.0 / ((double)NP * (double)NP),
        2.0 / ((double)NX * (double)NP),
        partials);

    // 3) combine
    finalize_kernel<<<1, THREADS, 0, stream>>>(partials, NBLOCKS, out);
}

// Round 4
// 54.392 us; speedup vs baseline: 4.2310x; 1.1556x over previous
//
#include <hip/hip_runtime.h>
#include <hip/hip_bf16.h>

#define THREADS 256
#define DIM 16

typedef __attribute__((ext_vector_type(8))) short bf16x8;
typedef __attribute__((ext_vector_type(16))) float f32x16;
typedef __attribute__((ext_vector_type(2))) float f32x2;

__device__ __forceinline__ float rawexp2(float a) { return __builtin_amdgcn_exp2f(a); }

// ---------------------------------------------------------------------------
// Prep: f32 -> bf16 RNE (truncation would bias each coordinate by -2^-9 and
// inject ~4.6e-6 bias into t1-t2). Three bf16 tensors:
//   xbs = RNE(L2E * x~)   (A-operand, pre-scaled by log2 e)
//   pbs = RNE(L2E * p~)   (A-operand for t1)
//   pb  = p~              (B-operand)
// Norms are computed FROM THE ROUNDED plain values and stored pre-scaled as
// -0.5*log2e*||v~||^2, so the gram kernel's pf is a bare load+exp and the t1
// diagonal cancels to ~ulp inside the MFMA (d = L2E*p2 - HL2E*p2 -> e*pf ~ 1).
// ---------------------------------------------------------------------------
__global__ __launch_bounds__(THREADS) void prep_kernel(
    const float* __restrict__ x, int nx,
    const float* __restrict__ p, int np,
    short* __restrict__ xbs, float* __restrict__ xn,
    short* __restrict__ pbs, short* __restrict__ pb, float* __restrict__ pn)
{
    const float L2E  = 1.44269504088896340736f;
    const float HL2E = 0.72134752044448170368f;
    int i = blockIdx.x * THREADS + threadIdx.x;
    const float* src; short* ds; short* dp; float* dn;
    if (i < nx) {
        src = x + (size_t)i * DIM; ds = xbs + (size_t)i * DIM; dp = nullptr; dn = xn + i;
    } else if (i < nx + np) {
        int j = i - nx;
        src = p + (size_t)j * DIM; ds = pbs + (size_t)j * DIM; dp = pb + (size_t)j * DIM; dn = pn + j;
    } else {
        return;
    }

    float nrm = 0.f;
    bf16x8 plo, phi, slo, shi;
#pragma unroll
    for (int k = 0; k < DIM; ++k) {
        unsigned u = __float_as_uint(src[k]);
        unsigned short r = (unsigned short)((u + 0x7FFFu + ((u >> 16) & 1u)) >> 16); // RNE
        float fr = __uint_as_float((unsigned)r << 16);
        nrm = fmaf(fr, fr, nrm);
        unsigned us = __float_as_uint(L2E * fr);
        unsigned short rs = (unsigned short)((us + 0x7FFFu + ((us >> 16) & 1u)) >> 16); // RNE
        if (k < 8) { plo[k] = (short)r; slo[k] = (short)rs; }
        else       { phi[k - 8] = (short)r; shi[k - 8] = (short)rs; }
    }
    *(bf16x8*)ds = slo; *((bf16x8*)ds + 1) = shi;
    if (dp) { *(bf16x8*)dp = plo; *((bf16x8*)dp + 1) = phi; }
    *dn = -HL2E * nrm;
}

// ---------------------------------------------------------------------------
// One 32-row-tile x ntiles 32-col-tiles gram partial sum.
// MFMA 32x32x16 bf16, A pre-scaled by L2E, C seeded with the row-norm term:
//   d[r] = L2E*dot - HL2E*||row||^2        (the exp2 argument, no VALU fma)
// Per element: { v_exp_f32, half a v_pk_fma_f32 }. Per tile: one pf exp.
//   A frag: lane l holds rows[row0 + (l&31)], k = (l>>5)*8 + i
//   B frag: lane l holds cols[ct*32 + (l&31)], k = (l>>5)*8 + i
//   D:      lane l, reg r -> row = (r&3) + 8*(r>>2) + 4*(l>>5), col = l&31
// e = 2^d can reach ~2^72 on the t1 diagonal (norm term deferred to pf) —
// no overflow, and e*pf = true kernel value <= ~1.
// ---------------------------------------------------------------------------
__device__ __forceinline__ float gram_phase(
    const short* __restrict__ rowsb, const float* __restrict__ rown,
    const short* __restrict__ colsb, const float* __restrict__ coln,
    int row0, int ct0, int ntiles, int l31, int half)
{
    bf16x8 afrag = *(const bf16x8*)(rowsb + (size_t)(row0 + l31) * DIM + half * 8);

    f32x16 cseed;
#pragma unroll
    for (int r = 0; r < 16; ++r) {
        int rrow = (r & 3) + 8 * (r >> 2) + 4 * half;
        cseed[r] = rown[row0 + rrow];     // = -HL2E*||row||^2 (prescaled in prep)
    }

    f32x2 acca = {0.f, 0.f}, accb = {0.f, 0.f};
    const short* bptr = colsb + ((size_t)ct0 * 32 + l31) * DIM + half * 8;
    const float* nptr = coln + ct0 * 32 + l31;

    for (int t = 0; t < ntiles; t += 2) {  // ntiles even by construction
#pragma unroll
        for (int u = 0; u < 2; ++u) {
            bf16x8 bfrag = *(const bf16x8*)(bptr + (size_t)(t + u) * 32 * DIM);
            float pf = rawexp2(nptr[(t + u) * 32]);   // 2^(-HL2E*||col||^2)
            f32x16 d = __builtin_amdgcn_mfma_f32_32x32x16_bf16(afrag, bfrag, cseed, 0, 0, 0);
            f32x2 pf2 = {pf, pf};
#pragma unroll
            for (int r = 0; r < 8; ++r) {
                f32x2 e = { rawexp2(d[2 * r]), rawexp2(d[2 * r + 1]) };
                if (r & 1) accb = e * pf2 + accb;   // v_pk_fma_f32
                else       acca = e * pf2 + acca;
            }
        }
    }
    f32x2 s = acca + accb;
    return s.x + s.y;
}

// ---------------------------------------------------------------------------
// Fused t1 + t2: 8192 waves, each exactly n1 t1-tiles + n2 t2-tiles.
// ---------------------------------------------------------------------------
__global__ __launch_bounds__(THREADS) void gram_fused_kernel(
    const short* __restrict__ xbs, const float* __restrict__ xn,
    const short* __restrict__ pbs, const short* __restrict__ pb,
    const float* __restrict__ pn,
    int nrt_p, int n1,
    int nrt_x, int n2,
    double sc1, double sc2,
    double* __restrict__ partials)
{
    const int lane = threadIdx.x & 63;
    const int wv   = threadIdx.x >> 6;
    const int l31  = lane & 31;
    const int half = lane >> 5;
    const int w    = blockIdx.x * (THREADS / 64) + wv;

    // t1: P x P  (rows = scaled particles, cols = plain particles)
    const int rt1 = w & (nrt_p - 1);
    const int c10 = (w / nrt_p) * n1;
    float acc1 = gram_phase(pbs, pn, pb, pn, rt1 * 32, c10, n1, l31, half);

    // t2: X x P
    const int rt2 = w & (nrt_x - 1);
    const int c20 = (w / nrt_x) * n2;
    float acc2 = gram_phase(xbs, xn, pb, pn, rt2 * 32, c20, n2, l31, half);

    double v = (double)acc1 * sc1 - (double)acc2 * sc2;
#pragma unroll
    for (int off = 32; off > 0; off >>= 1) v += __shfl_down(v, off);

    __shared__ double sred[THREADS / 64];
    if (lane == 0) sred[wv] = v;
    __syncthreads();
    if (threadIdx.x == 0) {
        double tot = 0.0;
#pragma unroll
        for (int q = 0; q < THREADS / 64; ++q) tot += sred[q];
        partials[blockIdx.x] = tot;
    }
}

__global__ __launch_bounds__(THREADS) void finalize_kernel(
    const double* __restrict__ partials, int n, float* __restrict__ out)
{
    double v = 0.0;
    for (int i = threadIdx.x; i < n; i += THREADS) v += partials[i];
#pragma unroll
    for (int off = 32; off > 0; off >>= 1) v += __shfl_down(v, off);

    __shared__ double sred[THREADS / 64];
    const int lane = threadIdx.x & 63;
    const int wid = threadIdx.x >> 6;
    if (lane == 0) sred[wid] = v;
    __syncthreads();
    if (threadIdx.x == 0) {
        double tot = 0.0;
#pragma unroll
        for (int q = 0; q < THREADS / 64; ++q) tot += sred[q];
        out[0] = (float)tot;
    }
}

extern "C" void kernel_launch(void* const* d_in, const int* in_sizes, int n_in,
                              void* d_out, int out_size, void* d_ws, size_t ws_size,
                              hipStream_t stream) {
    const float* x = (const float*)d_in[0];         // [NX, 16]
    const float* particles = (const float*)d_in[1]; // [NP, 16]
    float* out = (float*)d_out;

    const int NX = in_sizes[0] / DIM;  // 32768
    const int NP = in_sizes[1] / DIM;  // 8192

    const int nrt_x = NX / 32;         // 1024 (pow2)
    const int nrt_p = NP / 32;         // 256  (pow2)

    const int NBLOCKS = 2048;          // 8192 waves
    const int WAVES = NBLOCKS * (THREADS / 64);
    const int n1 = (nrt_p * nrt_p) / WAVES;  // 8  (even)
    const int n2 = (nrt_x * nrt_p) / WAVES;  // 32 (even)

    // ---- workspace layout (16B-aligned offsets) ----
    char* ws = (char*)d_ws;
    double* partials = (double*)ws;                  //     16 KB @ 0
    float*  xn  = (float*)(ws + 16384);              //    128 KB
    float*  pn  = (float*)(ws + 147456);             //     32 KB
    short*  xbs = (short*)(ws + 180224);             //   1 MB (scaled x)
    short*  pbs = (short*)(ws + 1228800);            //  256 KB (scaled p)
    short*  pb  = (short*)(ws + 1490944);            //  256 KB (plain p)

    // 1) convert + norms
    const int nprep = (NX + NP + THREADS - 1) / THREADS;
    prep_kernel<<<nprep, THREADS, 0, stream>>>(x, NX, particles, NP, xbs, xn, pbs, pb, pn);

    // 2) fused gram sums (scales applied per-wave in f64)
    gram_fused_kernel<<<NBLOCKS, THREADS, 0, stream>>>(
        xbs, xn, pbs, pb, pn,
        nrt_p, n1, nrt_x, n2,
        1.0 / ((double)NP * (double)NP),
        2.0 / ((double)NX * (double)NP),
        partials);

    // 3) combine
    finalize_kernel<<<1, THREADS, 0, stream>>>(partials, NBLOCKS, out);
}

// Round 5
// 51.962 us; speedup vs baseline: 4.4288x; 1.0468x over previous
//
#include <hip/hip_runtime.h>
#include <hip/hip_bf16.h>

#define THREADS 256
#define DIM 16

typedef __attribute__((ext_vector_type(8))) short bf16x8;
typedef __attribute__((ext_vector_type(16))) float f32x16;

__device__ __forceinline__ float rawexp2(float a) { return __builtin_amdgcn_exp2f(a); }

// ---------------------------------------------------------------------------
// Prep: f32 -> bf16 RNE (truncation would bias each coordinate by -2^-9 and
// inject ~4.6e-6 bias into t1-t2). Outputs:
//   xbs/pbs = RNE(L2E * v~)            (A-operands, pre-scaled by log2 e)
//   pb      = v~                       (B-operand, particles only)
//   xn/pn   = -0.5*log2e*||v~||^2      (C-seed row terms, f32)
//   pfp     = exp2(-0.5*log2e*||p~||^2) (per-column factor, PREcomputed so the
//             gram loop has no per-tile trans op / load->exp dependency)
// Norms from the ROUNDED plain values; the t1 diagonal then cancels to ~2^eta,
// eta ~ bf16 dot noise (random, ~1e-8 net on the output).
// ---------------------------------------------------------------------------
__global__ __launch_bounds__(THREADS) void prep_kernel(
    const float* __restrict__ x, int nx,
    const float* __restrict__ p, int np,
    short* __restrict__ xbs, float* __restrict__ xn,
    short* __restrict__ pbs, short* __restrict__ pb,
    float* __restrict__ pn, float* __restrict__ pfp)
{
    const float L2E  = 1.44269504088896340736f;
    const float HL2E = 0.72134752044448170368f;
    int i = blockIdx.x * THREADS + threadIdx.x;
    const float* src; short* ds; short* dp; float* dn; float* df;
    if (i < nx) {
        src = x + (size_t)i * DIM; ds = xbs + (size_t)i * DIM;
        dp = nullptr; dn = xn + i; df = nullptr;
    } else if (i < nx + np) {
        int j = i - nx;
        src = p + (size_t)j * DIM; ds = pbs + (size_t)j * DIM;
        dp = pb + (size_t)j * DIM; dn = pn + j; df = pfp + j;
    } else {
        return;
    }

    float nrm = 0.f;
    bf16x8 plo, phi, slo, shi;
#pragma unroll
    for (int k = 0; k < DIM; ++k) {
        unsigned u = __float_as_uint(src[k]);
        unsigned short r = (unsigned short)((u + 0x7FFFu + ((u >> 16) & 1u)) >> 16); // RNE
        float fr = __uint_as_float((unsigned)r << 16);
        nrm = fmaf(fr, fr, nrm);
        unsigned us = __float_as_uint(L2E * fr);
        unsigned short rs = (unsigned short)((us + 0x7FFFu + ((us >> 16) & 1u)) >> 16); // RNE
        if (k < 8) { plo[k] = (short)r; slo[k] = (short)rs; }
        else       { phi[k - 8] = (short)r; shi[k - 8] = (short)rs; }
    }
    *(bf16x8*)ds = slo; *((bf16x8*)ds + 1) = shi;
    if (dp) { *(bf16x8*)dp = plo; *((bf16x8*)dp + 1) = phi; }
    float ns = -HL2E * nrm;
    *dn = ns;
    if (df) *df = rawexp2(ns);
}

// ---------------------------------------------------------------------------
// One 32-row-tile x ntiles 32-col-tiles gram partial sum, software-pipelined:
//   - b-frag / pf prefetched one tile ahead (covers ~200cy L2 latency)
//   - MFMA result consumed one stage late (16-exp chain of tile t-1 hides
//     MFMA latency of tile t)
// MFMA 32x32x16 bf16, A pre-scaled by L2E, C seeded with -HL2E*||row||^2:
//   d[r] = L2E*dot - HL2E*||row||^2  -> e = 2^d, acc = fma(pf_col, sum(e), acc)
//   A/B frag: lane l holds point (l&31), k = (l>>5)*8 + i
//   D:        lane l, reg r -> row = (r&3) + 8*(r>>2) + 4*(l>>5), col = l&31
// All 16 d-elements of a lane share col (l&31) -> one pf per lane per tile.
// ---------------------------------------------------------------------------
__device__ __forceinline__ float gram_phase(
    const short* __restrict__ rowsb, const float* __restrict__ rown,
    const short* __restrict__ colsb, const float* __restrict__ colpf,
    int row0, int ct0, int ntiles, int l31, int half)
{
    bf16x8 afrag = *(const bf16x8*)(rowsb + (size_t)(row0 + l31) * DIM + half * 8);

    f32x16 cseed;
#pragma unroll
    for (int r = 0; r < 16; ++r) {
        int rrow = (r & 3) + 8 * (r >> 2) + 4 * half;
        cseed[r] = rown[row0 + rrow];      // = -HL2E*||row||^2 (prescaled)
    }

    const short* bptr = colsb + ((size_t)ct0 * 32 + l31) * DIM + half * 8;
    const float* fptr = colpf + ct0 * 32 + l31;
    const size_t bstride = (size_t)32 * DIM;

    // pipeline prologue (ntiles >= 2 always)
    bf16x8 bcur = *(const bf16x8*)bptr;
    float  fcur = *fptr;
    bf16x8 bnxt = *(const bf16x8*)(bptr + bstride);
    float  fnxt = fptr[32];

    f32x16 d = __builtin_amdgcn_mfma_f32_32x32x16_bf16(afrag, bcur, cseed, 0, 0, 0);
    float fuse = fcur;

    float acc0 = 0.f, acc1 = 0.f;

#pragma unroll 2
    for (int t = 1; t < ntiles; ++t) {
        int tn = (t + 1 < ntiles) ? t + 1 : t;   // clamped prefetch index
        bcur = bnxt; fcur = fnxt;
        bnxt = *(const bf16x8*)(bptr + (size_t)tn * bstride);
        fnxt = fptr[tn * 32];

        f32x16 dn = __builtin_amdgcn_mfma_f32_32x32x16_bf16(afrag, bcur, cseed, 0, 0, 0);

        // consume previous tile's result while dn is in flight
        float s0 = 0.f, s1 = 0.f;
#pragma unroll
        for (int r = 0; r < 16; r += 2) {
            s0 += rawexp2(d[r]);
            s1 += rawexp2(d[r + 1]);
        }
        acc0 = fmaf(fuse, s0, acc0);
        acc1 = fmaf(fuse, s1, acc1);

        d = dn; fuse = fcur;
    }
    {
        float s0 = 0.f, s1 = 0.f;
#pragma unroll
        for (int r = 0; r < 16; r += 2) {
            s0 += rawexp2(d[r]);
            s1 += rawexp2(d[r + 1]);
        }
        acc0 = fmaf(fuse, s0, acc0);
        acc1 = fmaf(fuse, s1, acc1);
    }
    return acc0 + acc1;
}

// ---------------------------------------------------------------------------
// Fused t1 + t2: 8192 waves, each exactly n1 t1-tiles + n2 t2-tiles.
// ---------------------------------------------------------------------------
__global__ __launch_bounds__(THREADS) void gram_fused_kernel(
    const short* __restrict__ xbs, const float* __restrict__ xn,
    const short* __restrict__ pbs, const short* __restrict__ pb,
    const float* __restrict__ pn, const float* __restrict__ pfp,
    int nrt_p, int n1,
    int nrt_x, int n2,
    double sc1, double sc2,
    double* __restrict__ partials)
{
    const int lane = threadIdx.x & 63;
    const int wv   = threadIdx.x >> 6;
    const int l31  = lane & 31;
    const int half = lane >> 5;
    const int w    = blockIdx.x * (THREADS / 64) + wv;

    // t1: P x P  (rows = scaled particles, cols = plain particles)
    const int rt1 = w & (nrt_p - 1);
    const int c10 = (w / nrt_p) * n1;
    float acc1 = gram_phase(pbs, pn, pb, pfp, rt1 * 32, c10, n1, l31, half);

    // t2: X x P
    const int rt2 = w & (nrt_x - 1);
    const int c20 = (w / nrt_x) * n2;
    float acc2 = gram_phase(xbs, xn, pb, pfp, rt2 * 32, c20, n2, l31, half);

    double v = (double)acc1 * sc1 - (double)acc2 * sc2;
#pragma unroll
    for (int off = 32; off > 0; off >>= 1) v += __shfl_down(v, off);

    __shared__ double sred[THREADS / 64];
    if (lane == 0) sred[wv] = v;
    __syncthreads();
    if (threadIdx.x == 0) {
        double tot = 0.0;
#pragma unroll
        for (int q = 0; q < THREADS / 64; ++q) tot += sred[q];
        partials[blockIdx.x] = tot;
    }
}

__global__ __launch_bounds__(THREADS) void finalize_kernel(
    const double* __restrict__ partials, int n, float* __restrict__ out)
{
    double v = 0.0;
    for (int i = threadIdx.x; i < n; i += THREADS) v += partials[i];
#pragma unroll
    for (int off = 32; off > 0; off >>= 1) v += __shfl_down(v, off);

    __shared__ double sred[THREADS / 64];
    const int lane = threadIdx.x & 63;
    const int wid = threadIdx.x >> 6;
    if (lane == 0) sred[wid] = v;
    __syncthreads();
    if (threadIdx.x == 0) {
        double tot = 0.0;
#pragma unroll
        for (int q = 0; q < THREADS / 64; ++q) tot += sred[q];
        out[0] = (float)tot;
    }
}

extern "C" void kernel_launch(void* const* d_in, const int* in_sizes, int n_in,
                              void* d_out, int out_size, void* d_ws, size_t ws_size,
                              hipStream_t stream) {
    const float* x = (const float*)d_in[0];         // [NX, 16]
    const float* particles = (const float*)d_in[1]; // [NP, 16]
    float* out = (float*)d_out;

    const int NX = in_sizes[0] / DIM;  // 32768
    const int NP = in_sizes[1] / DIM;  // 8192

    const int nrt_x = NX / 32;         // 1024 (pow2)
    const int nrt_p = NP / 32;         // 256  (pow2)

    const int NBLOCKS = 2048;          // 8192 waves
    const int WAVES = NBLOCKS * (THREADS / 64);
    const int n1 = (nrt_p * nrt_p) / WAVES;  // 8
    const int n2 = (nrt_x * nrt_p) / WAVES;  // 32

    // ---- workspace layout (16B-aligned offsets) ----
    char* ws = (char*)d_ws;
    double* partials = (double*)ws;                  //   16 KB @ 0
    float*  xn  = (float*)(ws + 16384);              //  128 KB
    float*  pn  = (float*)(ws + 147456);             //   32 KB
    float*  pfp = (float*)(ws + 180224);             //   32 KB
    short*  xbs = (short*)(ws + 212992);             //    1 MB (scaled x)
    short*  pbs = (short*)(ws + 1261568);            //  256 KB (scaled p)
    short*  pb  = (short*)(ws + 1523712);            //  256 KB (plain p)

    // 1) convert + norms + column factors
    const int nprep = (NX + NP + THREADS - 1) / THREADS;
    prep_kernel<<<nprep, THREADS, 0, stream>>>(x, NX, particles, NP,
                                               xbs, xn, pbs, pb, pn, pfp);

    // 2) fused gram sums (scales applied per-wave in f64)
    gram_fused_kernel<<<NBLOCKS, THREADS, 0, stream>>>(
        xbs, xn, pbs, pb, pn, pfp,
        nrt_p, n1, nrt_x, n2,
        1.0 / ((double)NP * (double)NP),
        2.0 / ((double)NX * (double)NP),
        partials);

    // 3) combine
    finalize_kernel<<<1, THREADS, 0, stream>>>(partials, NBLOCKS, out);
}

// Round 6
// 51.178 us; speedup vs baseline: 4.4967x; 1.0153x over previous
//
#include <hip/hip_runtime.h>
#include <hip/hip_bf16.h>

#define THREADS 256
#define DIM 16

typedef __attribute__((ext_vector_type(8))) short bf16x8;
typedef __attribute__((ext_vector_type(16))) float f32x16;
typedef __attribute__((ext_vector_type(2))) float f32x2;

__device__ __forceinline__ float rawexp2(float a) { return __builtin_amdgcn_exp2f(a); }

// ---------------------------------------------------------------------------
// Prep: f32 -> bf16 RNE (truncation would bias each coordinate by -2^-9 and
// inject ~4.6e-6 bias into t1-t2). Outputs:
//   xbs/pbs = RNE(L2E * v~)             (A-operands, pre-scaled by log2 e)
//   pb      = v~                        (B-operand, particles only)
//   xn/pn   = -0.5*log2e*||v~||^2       (C-seed row terms, f32)
//   pfp     = exp2(-0.5*log2e*||p~||^2) (per-column factor, precomputed)
// Norms from the ROUNDED plain values; the t1 diagonal cancels to ~2^eta,
// eta ~ bf16 dot noise (random, ~1e-8 net on the output).
// ---------------------------------------------------------------------------
__global__ __launch_bounds__(THREADS) void prep_kernel(
    const float* __restrict__ x, int nx,
    const float* __restrict__ p, int np,
    short* __restrict__ xbs, float* __restrict__ xn,
    short* __restrict__ pbs, short* __restrict__ pb,
    float* __restrict__ pn, float* __restrict__ pfp)
{
    const float L2E  = 1.44269504088896340736f;
    const float HL2E = 0.72134752044448170368f;
    int i = blockIdx.x * THREADS + threadIdx.x;
    const float* src; short* ds; short* dp; float* dn; float* df;
    if (i < nx) {
        src = x + (size_t)i * DIM; ds = xbs + (size_t)i * DIM;
        dp = nullptr; dn = xn + i; df = nullptr;
    } else if (i < nx + np) {
        int j = i - nx;
        src = p + (size_t)j * DIM; ds = pbs + (size_t)j * DIM;
        dp = pb + (size_t)j * DIM; dn = pn + j; df = pfp + j;
    } else {
        return;
    }

    float nrm = 0.f;
    bf16x8 plo, phi, slo, shi;
#pragma unroll
    for (int k = 0; k < DIM; ++k) {
        unsigned u = __float_as_uint(src[k]);
        unsigned short r = (unsigned short)((u + 0x7FFFu + ((u >> 16) & 1u)) >> 16); // RNE
        float fr = __uint_as_float((unsigned)r << 16);
        nrm = fmaf(fr, fr, nrm);
        unsigned us = __float_as_uint(L2E * fr);
        unsigned short rs = (unsigned short)((us + 0x7FFFu + ((us >> 16) & 1u)) >> 16); // RNE
        if (k < 8) { plo[k] = (short)r; slo[k] = (short)rs; }
        else       { phi[k - 8] = (short)r; shi[k - 8] = (short)rs; }
    }
    *(bf16x8*)ds = slo; *((bf16x8*)ds + 1) = shi;
    if (dp) { *(bf16x8*)dp = plo; *((bf16x8*)dp + 1) = phi; }
    float ns = -HL2E * nrm;
    *dn = ns;
    if (df) *df = rawexp2(ns);
}

// Consume one MFMA result: 16 raw v_exp_f32 + 8 v_pk_fma_f32.
__device__ __forceinline__ void consume_tile(const f32x16& d, float f, f32x2& acc)
{
    f32x2 pf2 = {f, f};
#pragma unroll
    for (int r = 0; r < 8; ++r) {
        f32x2 e = { rawexp2(d[2 * r]), rawexp2(d[2 * r + 1]) };
        acc = e * pf2 + acc;
    }
}

// ---------------------------------------------------------------------------
// One 32-row-tile x ntiles 32-col-tiles gram partial sum.
// Ping-pong pipeline (d0/d1, static names -> no f32x16 rotation movs):
//   per 2 tiles: prefetch next-pair b/f, consume d0, remfma d0,
//                consume d1, remfma d1.
// MFMA 32x32x16 bf16, A pre-scaled by L2E, C seeded with -HL2E*||row||^2:
//   d[r] = L2E*dot - HL2E*||row||^2 ; e = 2^d ; acc = pk_fma(e, pf_col, acc)
//   A/B frag: lane l holds point (l&31), k = (l>>5)*8 + i
//   D:        lane l, reg r -> row = (r&3) + 8*(r>>2) + 4*(l>>5), col = l&31
// All 16 d-elements of a lane share col (l&31) -> one pf per lane per tile.
// e = 2^d can reach ~2^72 on the t1 diagonal; no overflow, e*pf <= ~1.
// ntiles must be even and >= 2 (8 and 32 here).
// ---------------------------------------------------------------------------
__device__ __forceinline__ float gram_phase(
    const short* __restrict__ rowsb, const float* __restrict__ rown,
    const short* __restrict__ colsb, const float* __restrict__ colpf,
    int row0, int ct0, int ntiles, int l31, int half)
{
    bf16x8 afrag = *(const bf16x8*)(rowsb + (size_t)(row0 + l31) * DIM + half * 8);

    f32x16 cseed;
#pragma unroll
    for (int r = 0; r < 16; ++r) {
        int rrow = (r & 3) + 8 * (r >> 2) + 4 * half;
        cseed[r] = rown[row0 + rrow];      // = -HL2E*||row||^2 (prescaled)
    }

    const short* bptr = colsb + ((size_t)ct0 * 32 + l31) * DIM + half * 8;
    const float* fptr = colpf + ct0 * 32 + l31;
    const size_t bstride = (size_t)32 * DIM;

    bf16x8 b0 = *(const bf16x8*)bptr;
    bf16x8 b1 = *(const bf16x8*)(bptr + bstride);
    float  f0 = fptr[0];
    float  f1 = fptr[32];

    f32x16 d0 = __builtin_amdgcn_mfma_f32_32x32x16_bf16(afrag, b0, cseed, 0, 0, 0);
    f32x16 d1 = __builtin_amdgcn_mfma_f32_32x32x16_bf16(afrag, b1, cseed, 0, 0, 0);

    f32x2 acc = {0.f, 0.f};

    for (int t = 0; t + 2 < ntiles; t += 2) {
        // prefetch next pair before consuming current pair (~250cy lead)
        bf16x8 bn0 = *(const bf16x8*)(bptr + (size_t)(t + 2) * bstride);
        float  fn0 = fptr[(t + 2) * 32];
        bf16x8 bn1 = *(const bf16x8*)(bptr + (size_t)(t + 3) * bstride);
        float  fn1 = fptr[(t + 3) * 32];

        consume_tile(d0, f0, acc);
        d0 = __builtin_amdgcn_mfma_f32_32x32x16_bf16(afrag, bn0, cseed, 0, 0, 0);
        consume_tile(d1, f1, acc);
        d1 = __builtin_amdgcn_mfma_f32_32x32x16_bf16(afrag, bn1, cseed, 0, 0, 0);

        f0 = fn0; f1 = fn1;
    }
    consume_tile(d0, f0, acc);
    consume_tile(d1, f1, acc);
    return acc.x + acc.y;
}

// ---------------------------------------------------------------------------
// Fused t1 + t2: 8192 waves, each exactly n1 t1-tiles + n2 t2-tiles.
// ---------------------------------------------------------------------------
__global__ __launch_bounds__(THREADS) void gram_fused_kernel(
    const short* __restrict__ xbs, const float* __restrict__ xn,
    const short* __restrict__ pbs, const short* __restrict__ pb,
    const float* __restrict__ pn, const float* __restrict__ pfp,
    int nrt_p, int n1,
    int nrt_x, int n2,
    double sc1, double sc2,
    double* __restrict__ partials)
{
    const int lane = threadIdx.x & 63;
    const int wv   = threadIdx.x >> 6;
    const int l31  = lane & 31;
    const int half = lane >> 5;
    const int w    = blockIdx.x * (THREADS / 64) + wv;

    // t1: P x P  (rows = scaled particles, cols = plain particles)
    const int rt1 = w & (nrt_p - 1);
    const int c10 = (w / nrt_p) * n1;
    float acc1 = gram_phase(pbs, pn, pb, pfp, rt1 * 32, c10, n1, l31, half);

    // t2: X x P
    const int rt2 = w & (nrt_x - 1);
    const int c20 = (w / nrt_x) * n2;
    float acc2 = gram_phase(xbs, xn, pb, pfp, rt2 * 32, c20, n2, l31, half);

    double v = (double)acc1 * sc1 - (double)acc2 * sc2;
#pragma unroll
    for (int off = 32; off > 0; off >>= 1) v += __shfl_down(v, off);

    __shared__ double sred[THREADS / 64];
    if (lane == 0) sred[wv] = v;
    __syncthreads();
    if (threadIdx.x == 0) {
        double tot = 0.0;
#pragma unroll
        for (int q = 0; q < THREADS / 64; ++q) tot += sred[q];
        partials[blockIdx.x] = tot;
    }
}

__global__ __launch_bounds__(THREADS) void finalize_kernel(
    const double* __restrict__ partials, int n, float* __restrict__ out)
{
    double v = 0.0;
    for (int i = threadIdx.x; i < n; i += THREADS) v += partials[i];
#pragma unroll
    for (int off = 32; off > 0; off >>= 1) v += __shfl_down(v, off);

    __shared__ double sred[THREADS / 64];
    const int lane = threadIdx.x & 63;
    const int wid = threadIdx.x >> 6;
    if (lane == 0) sred[wid] = v;
    __syncthreads();
    if (threadIdx.x == 0) {
        double tot = 0.0;
#pragma unroll
        for (int q = 0; q < THREADS / 64; ++q) tot += sred[q];
        out[0] = (float)tot;
    }
}

extern "C" void kernel_launch(void* const* d_in, const int* in_sizes, int n_in,
                              void* d_out, int out_size, void* d_ws, size_t ws_size,
                              hipStream_t stream) {
    const float* x = (const float*)d_in[0];         // [NX, 16]
    const float* particles = (const float*)d_in[1]; // [NP, 16]
    float* out = (float*)d_out;

    const int NX = in_sizes[0] / DIM;  // 32768
    const int NP = in_sizes[1] / DIM;  // 8192

    const int nrt_x = NX / 32;         // 1024 (pow2)
    const int nrt_p = NP / 32;         // 256  (pow2)

    const int NBLOCKS = 2048;          // 8192 waves
    const int WAVES = NBLOCKS * (THREADS / 64);
    const int n1 = (nrt_p * nrt_p) / WAVES;  // 8  (even)
    const int n2 = (nrt_x * nrt_p) / WAVES;  // 32 (even)

    // ---- workspace layout (16B-aligned offsets) ----
    char* ws = (char*)d_ws;
    double* partials = (double*)ws;                  //   16 KB @ 0
    float*  xn  = (float*)(ws + 16384);              //  128 KB
    float*  pn  = (float*)(ws + 147456);             //   32 KB
    float*  pfp = (float*)(ws + 180224);             //   32 KB
    short*  xbs = (short*)(ws + 212992);             //    1 MB (scaled x)
    short*  pbs = (short*)(ws + 1261568);            //  256 KB (scaled p)
    short*  pb  = (short*)(ws + 1523712);            //  256 KB (plain p)

    // 1) convert + norms + column factors
    const int nprep = (NX + NP + THREADS - 1) / THREADS;
    prep_kernel<<<nprep, THREADS, 0, stream>>>(x, NX, particles, NP,
                                               xbs, xn, pbs, pb, pn, pfp);

    // 2) fused gram sums (scales applied per-wave in f64)
    gram_fused_kernel<<<NBLOCKS, THREADS, 0, stream>>>(
        xbs, xn, pbs, pb, pn, pfp,
        nrt_p, n1, nrt_x, n2,
        1.0 / ((double)NP * (double)NP),
        2.0 / ((double)NX * (double)NP),
        partials);

    // 3) combine
    finalize_kernel<<<1, THREADS, 0, stream>>>(partials, NBLOCKS, out);
}

// Round 7
// 50.719 us; speedup vs baseline: 4.5374x; 1.0090x over previous
//
#include <hip/hip_runtime.h>
#include <hip/hip_bf16.h>

#define THREADS 256
#define DIM 16

typedef __attribute__((ext_vector_type(8))) short bf16x8;
typedef __attribute__((ext_vector_type(16))) float f32x16;
typedef __attribute__((ext_vector_type(2))) float f32x2;

__device__ __forceinline__ float rawexp2(float a) { return __builtin_amdgcn_exp2f(a); }

// ---------------------------------------------------------------------------
// Prep: f32 -> bf16 RNE (truncation would bias each coordinate by -2^-9 and
// inject ~4.6e-6 bias into t1-t2). Outputs:
//   xbs/pbs = RNE(L2E * v~)             (A-operands, pre-scaled by log2 e)
//   pb      = v~                        (B-operand, particles only)
//   xn/pn   = -0.5*log2e*||v~||^2       (C-seed row terms, f32)
//   pfp     = exp2(-0.5*log2e*||p~||^2) (per-column factor, precomputed)
// Norms from the ROUNDED plain values; the t1 diagonal cancels to ~2^eta,
// eta ~ bf16 dot noise (random, ~1e-8 net on the output).
// ---------------------------------------------------------------------------
__global__ __launch_bounds__(THREADS) void prep_kernel(
    const float* __restrict__ x, int nx,
    const float* __restrict__ p, int np,
    short* __restrict__ xbs, float* __restrict__ xn,
    short* __restrict__ pbs, short* __restrict__ pb,
    float* __restrict__ pn, float* __restrict__ pfp)
{
    const float L2E  = 1.44269504088896340736f;
    const float HL2E = 0.72134752044448170368f;
    int i = blockIdx.x * THREADS + threadIdx.x;
    const float* src; short* ds; short* dp; float* dn; float* df;
    if (i < nx) {
        src = x + (size_t)i * DIM; ds = xbs + (size_t)i * DIM;
        dp = nullptr; dn = xn + i; df = nullptr;
    } else if (i < nx + np) {
        int j = i - nx;
        src = p + (size_t)j * DIM; ds = pbs + (size_t)j * DIM;
        dp = pb + (size_t)j * DIM; dn = pn + j; df = pfp + j;
    } else {
        return;
    }

    float nrm = 0.f;
    bf16x8 plo, phi, slo, shi;
#pragma unroll
    for (int k = 0; k < DIM; ++k) {
        unsigned u = __float_as_uint(src[k]);
        unsigned short r = (unsigned short)((u + 0x7FFFu + ((u >> 16) & 1u)) >> 16); // RNE
        float fr = __uint_as_float((unsigned)r << 16);
        nrm = fmaf(fr, fr, nrm);
        unsigned us = __float_as_uint(L2E * fr);
        unsigned short rs = (unsigned short)((us + 0x7FFFu + ((us >> 16) & 1u)) >> 16); // RNE
        if (k < 8) { plo[k] = (short)r; slo[k] = (short)rs; }
        else       { phi[k - 8] = (short)r; shi[k - 8] = (short)rs; }
    }
    *(bf16x8*)ds = slo; *((bf16x8*)ds + 1) = shi;
    if (dp) { *(bf16x8*)dp = plo; *((bf16x8*)dp + 1) = phi; }
    float ns = -HL2E * nrm;
    *dn = ns;
    if (df) *df = rawexp2(ns);
}

// Consume one MFMA result: 16 raw v_exp_f32 + 8 v_pk_fma_f32.
__device__ __forceinline__ void consume_tile(const f32x16& d, float f, f32x2& acc)
{
    f32x2 pf2 = {f, f};
#pragma unroll
    for (int r = 0; r < 8; ++r) {
        f32x2 e = { rawexp2(d[2 * r]), rawexp2(d[2 * r + 1]) };
        acc = e * pf2 + acc;
    }
}

// ---------------------------------------------------------------------------
// One 32-row-tile x ntiles 32-col-tiles gram partial sum.
// Ping-pong pipeline (d0/d1, static names -> no f32x16 rotation movs):
//   per 2 tiles: prefetch next-pair b/f, consume d0, remfma d0,
//                consume d1, remfma d1.
// MFMA 32x32x16 bf16, A pre-scaled by L2E, C seeded with -HL2E*||row||^2:
//   d[r] = L2E*dot - HL2E*||row||^2 ; e = 2^d ; acc = pk_fma(e, pf_col, acc)
//   A/B frag: lane l holds point (l&31), k = (l>>5)*8 + i
//   D:        lane l, reg r -> row = (r&3) + 8*(r>>2) + 4*(l>>5), col = l&31
// All 16 d-elements of a lane share col (l&31) -> one pf per lane per tile.
// e = 2^d can reach ~2^72 on the t1 diagonal; no overflow, e*pf <= ~1.
// ntiles must be even and >= 2 (16 and 64 here).
// ---------------------------------------------------------------------------
__device__ __forceinline__ float gram_phase(
    const short* __restrict__ rowsb, const float* __restrict__ rown,
    const short* __restrict__ colsb, const float* __restrict__ colpf,
    int row0, int ct0, int ntiles, int l31, int half)
{
    bf16x8 afrag = *(const bf16x8*)(rowsb + (size_t)(row0 + l31) * DIM + half * 8);

    f32x16 cseed;
#pragma unroll
    for (int r = 0; r < 16; ++r) {
        int rrow = (r & 3) + 8 * (r >> 2) + 4 * half;
        cseed[r] = rown[row0 + rrow];      // = -HL2E*||row||^2 (prescaled)
    }

    const short* bptr = colsb + ((size_t)ct0 * 32 + l31) * DIM + half * 8;
    const float* fptr = colpf + ct0 * 32 + l31;
    const size_t bstride = (size_t)32 * DIM;

    bf16x8 b0 = *(const bf16x8*)bptr;
    bf16x8 b1 = *(const bf16x8*)(bptr + bstride);
    float  f0 = fptr[0];
    float  f1 = fptr[32];

    f32x16 d0 = __builtin_amdgcn_mfma_f32_32x32x16_bf16(afrag, b0, cseed, 0, 0, 0);
    f32x16 d1 = __builtin_amdgcn_mfma_f32_32x32x16_bf16(afrag, b1, cseed, 0, 0, 0);

    f32x2 acc = {0.f, 0.f};

    for (int t = 0; t + 2 < ntiles; t += 2) {
        // prefetch next pair before consuming current pair (~250cy lead)
        bf16x8 bn0 = *(const bf16x8*)(bptr + (size_t)(t + 2) * bstride);
        float  fn0 = fptr[(t + 2) * 32];
        bf16x8 bn1 = *(const bf16x8*)(bptr + (size_t)(t + 3) * bstride);
        float  fn1 = fptr[(t + 3) * 32];

        consume_tile(d0, f0, acc);
        d0 = __builtin_amdgcn_mfma_f32_32x32x16_bf16(afrag, bn0, cseed, 0, 0, 0);
        consume_tile(d1, f1, acc);
        d1 = __builtin_amdgcn_mfma_f32_32x32x16_bf16(afrag, bn1, cseed, 0, 0, 0);

        f0 = fn0; f1 = fn1;
    }
    consume_tile(d0, f0, acc);
    consume_tile(d1, f1, acc);
    return acc.x + acc.y;
}

// ---------------------------------------------------------------------------
// Fused t1 + t2: 4096 waves (1024 blocks = exactly 4 blocks/CU, ALL resident
// simultaneously at 76 VGPR -> zero scheduling tail, perfect static balance).
// Each wave: exactly n1 t1-tiles + n2 t2-tiles.
// ---------------------------------------------------------------------------
__global__ __launch_bounds__(THREADS) void gram_fused_kernel(
    const short* __restrict__ xbs, const float* __restrict__ xn,
    const short* __restrict__ pbs, const short* __restrict__ pb,
    const float* __restrict__ pn, const float* __restrict__ pfp,
    int nrt_p, int n1,
    int nrt_x, int n2,
    double sc1, double sc2,
    double* __restrict__ partials)
{
    const int lane = threadIdx.x & 63;
    const int wv   = threadIdx.x >> 6;
    const int l31  = lane & 31;
    const int half = lane >> 5;
    const int w    = blockIdx.x * (THREADS / 64) + wv;

    // t1: P x P  (rows = scaled particles, cols = plain particles)
    const int rt1 = w & (nrt_p - 1);
    const int c10 = (w / nrt_p) * n1;
    float acc1 = gram_phase(pbs, pn, pb, pfp, rt1 * 32, c10, n1, l31, half);

    // t2: X x P
    const int rt2 = w & (nrt_x - 1);
    const int c20 = (w / nrt_x) * n2;
    float acc2 = gram_phase(xbs, xn, pb, pfp, rt2 * 32, c20, n2, l31, half);

    double v = (double)acc1 * sc1 - (double)acc2 * sc2;
#pragma unroll
    for (int off = 32; off > 0; off >>= 1) v += __shfl_down(v, off);

    __shared__ double sred[THREADS / 64];
    if (lane == 0) sred[wv] = v;
    __syncthreads();
    if (threadIdx.x == 0) {
        double tot = 0.0;
#pragma unroll
        for (int q = 0; q < THREADS / 64; ++q) tot += sred[q];
        partials[blockIdx.x] = tot;
    }
}

__global__ __launch_bounds__(THREADS) void finalize_kernel(
    const double* __restrict__ partials, int n, float* __restrict__ out)
{
    double v = 0.0;
    for (int i = threadIdx.x; i < n; i += THREADS) v += partials[i];
#pragma unroll
    for (int off = 32; off > 0; off >>= 1) v += __shfl_down(v, off);

    __shared__ double sred[THREADS / 64];
    const int lane = threadIdx.x & 63;
    const int wid = threadIdx.x >> 6;
    if (lane == 0) sred[wid] = v;
    __syncthreads();
    if (threadIdx.x == 0) {
        double tot = 0.0;
#pragma unroll
        for (int q = 0; q < THREADS / 64; ++q) tot += sred[q];
        out[0] = (float)tot;
    }
}

extern "C" void kernel_launch(void* const* d_in, const int* in_sizes, int n_in,
                              void* d_out, int out_size, void* d_ws, size_t ws_size,
                              hipStream_t stream) {
    const float* x = (const float*)d_in[0];         // [NX, 16]
    const float* particles = (const float*)d_in[1]; // [NP, 16]
    float* out = (float*)d_out;

    const int NX = in_sizes[0] / DIM;  // 32768
    const int NP = in_sizes[1] / DIM;  // 8192

    const int nrt_x = NX / 32;         // 1024 (pow2)
    const int nrt_p = NP / 32;         // 256  (pow2)

    // 1024 blocks = 4 blocks/CU exactly; 16 waves/CU all resident (VGPR 76
    // -> 4 waves/SIMD x 76 = 304 <= 512). Zero tail, perfect balance.
    const int NBLOCKS = 1024;          // 4096 waves
    const int WAVES = NBLOCKS * (THREADS / 64);
    const int n1 = (nrt_p * nrt_p) / WAVES;  // 16 (even)
    const int n2 = (nrt_x * nrt_p) / WAVES;  // 64 (even)

    // ---- workspace layout (16B-aligned offsets) ----
    char* ws = (char*)d_ws;
    double* partials = (double*)ws;                  //    8 KB @ 0
    float*  xn  = (float*)(ws + 16384);              //  128 KB
    float*  pn  = (float*)(ws + 147456);             //   32 KB
    float*  pfp = (float*)(ws + 180224);             //   32 KB
    short*  xbs = (short*)(ws + 212992);             //    1 MB (scaled x)
    short*  pbs = (short*)(ws + 1261568);            //  256 KB (scaled p)
    short*  pb  = (short*)(ws + 1523712);            //  256 KB (plain p)

    // 1) convert + norms + column factors
    const int nprep = (NX + NP + THREADS - 1) / THREADS;
    prep_kernel<<<nprep, THREADS, 0, stream>>>(x, NX, particles, NP,
                                               xbs, xn, pbs, pb, pn, pfp);

    // 2) fused gram sums (scales applied per-wave in f64)
    gram_fused_kernel<<<NBLOCKS, THREADS, 0, stream>>>(
        xbs, xn, pbs, pb, pn, pfp,
        nrt_p, n1, nrt_x, n2,
        1.0 / ((double)NP * (double)NP),
        2.0 / ((double)NX * (double)NP),
        partials);

    // 3) combine
    finalize_kernel<<<1, THREADS, 0, stream>>>(partials, NBLOCKS, out);
}